// Round 1
// baseline (2843.695 us; speedup 1.0000x reference)
//
#include <hip/hip_runtime.h>

#define NN 100000
#define NE 1600000
#define F 64

// ---------------- node transform: f_ni = x@W_ni^T, f_nj = x@W_nj^T, h = x@W_node^T + b ----------------
// lane = node. Node row lives in 64 VGPRs; W accesses are wave-uniform -> scalar loads.
__global__ __launch_bounds__(256) void node_kernel(
    const float* __restrict__ nfeats,
    const float* __restrict__ W_node, const float* __restrict__ b_node,
    const float* __restrict__ W_ni,   const float* __restrict__ W_nj,
    float* __restrict__ f_ni, float* __restrict__ f_nj, float* __restrict__ h)
{
    const int n = blockIdx.x * 256 + threadIdx.x;
    if (n >= NN) return;
    float x[F];
    const float4* xr = reinterpret_cast<const float4*>(nfeats + (size_t)n * F);
#pragma unroll
    for (int i = 0; i < F / 4; ++i) reinterpret_cast<float4*>(x)[i] = xr[i];

    float4* po = reinterpret_cast<float4*>(f_ni + (size_t)n * F);
    float4* qo = reinterpret_cast<float4*>(f_nj + (size_t)n * F);
    float4* ho = reinterpret_cast<float4*>(h    + (size_t)n * F);

    for (int oc = 0; oc < F; oc += 4) {
        float ai[4], aj[4], ah[4];
#pragma unroll
        for (int j = 0; j < 4; ++j) { ai[j] = 0.f; aj[j] = 0.f; ah[j] = b_node[oc + j]; }
#pragma unroll
        for (int k = 0; k < F; ++k) {
            const float xv = x[k];
#pragma unroll
            for (int j = 0; j < 4; ++j) {
                ai[j] += xv * W_ni  [(oc + j) * F + k];   // uniform address -> s_load
                aj[j] += xv * W_nj  [(oc + j) * F + k];
                ah[j] += xv * W_node[(oc + j) * F + k];
            }
        }
        po[oc >> 2] = make_float4(ai[0], ai[1], ai[2], ai[3]);
        qo[oc >> 2] = make_float4(aj[0], aj[1], aj[2], aj[3]);
        ho[oc >> 2] = make_float4(ah[0], ah[1], ah[2], ah[3]);
    }
}

// ---------------- edge update: f_out = leaky_relu(f_ni[src] + f_nj[dst] + efeats@W_fij^T + bias) -------
// lane = edge. Edge row in 64 VGPRs; W_fij via uniform scalar loads; gathers hit L3.
__global__ __launch_bounds__(256) void edge_kernel(
    const float* __restrict__ efeats,
    const int* __restrict__ src, const int* __restrict__ dst,
    const float* __restrict__ f_ni, const float* __restrict__ f_nj,
    const float* __restrict__ W_fij, const float* __restrict__ bias,
    float* __restrict__ f_out)
{
    const int e = blockIdx.x * 256 + threadIdx.x;
    if (e >= NE) return;
    const int s = src[e], d = dst[e];
    float x[F];
    const float4* xr = reinterpret_cast<const float4*>(efeats + (size_t)e * F);
#pragma unroll
    for (int i = 0; i < F / 4; ++i) reinterpret_cast<float4*>(x)[i] = xr[i];

    const float4* gi = reinterpret_cast<const float4*>(f_ni + (size_t)s * F);
    const float4* gj = reinterpret_cast<const float4*>(f_nj + (size_t)d * F);
    float4* out = reinterpret_cast<float4*>(f_out + (size_t)e * F);

    for (int oc = 0; oc < F; oc += 4) {
        float a[4];
#pragma unroll
        for (int j = 0; j < 4; ++j) a[j] = bias[oc + j];
#pragma unroll
        for (int k = 0; k < F; ++k) {
            const float xv = x[k];
#pragma unroll
            for (int j = 0; j < 4; ++j) a[j] += xv * W_fij[(oc + j) * F + k];  // uniform -> s_load
        }
        const float4 v1 = gi[oc >> 2];
        const float4 v2 = gj[oc >> 2];
        a[0] += v1.x + v2.x;
        a[1] += v1.y + v2.y;
        a[2] += v1.z + v2.z;
        a[3] += v1.w + v2.w;
#pragma unroll
        for (int j = 0; j < 4; ++j) a[j] = (a[j] > 0.f) ? a[j] : 0.01f * a[j];
        out[oc >> 2] = make_float4(a[0], a[1], a[2], a[3]);
    }
}

// ---------------- aggregation: msg_sum[dst] += h[src]; deg[dst] += 1 ----------------
// thread per (edge, 4 columns): coalesced h-row read, 4 fp32 atomics.
__global__ __launch_bounds__(256) void msg_kernel(
    const float* __restrict__ h,
    const int* __restrict__ src, const int* __restrict__ dst,
    float* __restrict__ msg, float* __restrict__ deg)
{
    const long long gid = (long long)blockIdx.x * 256 + threadIdx.x;
    if (gid >= (long long)NE * 16) return;
    const int e = (int)(gid >> 4);
    const int c = ((int)gid & 15) << 2;
    const int s = src[e], d = dst[e];
    const float4 v = *reinterpret_cast<const float4*>(h + (size_t)s * F + c);
    float* m = msg + (size_t)d * F + c;
    atomicAdd(m + 0, v.x);
    atomicAdd(m + 1, v.y);
    atomicAdd(m + 2, v.z);
    atomicAdd(m + 3, v.w);
    if (c == 0) atomicAdd(deg + d, 1.0f);
}

// ---------------- h_out = msg_sum / max(deg, 1) ----------------
__global__ __launch_bounds__(256) void final_kernel(
    float* __restrict__ hout, const float* __restrict__ deg)
{
    const int i = blockIdx.x * 256 + threadIdx.x;
    if (i >= NN * F) return;
    const float dg = deg[i >> 6];
    hout[i] = hout[i] / fmaxf(dg, 1.0f);
}

extern "C" void kernel_launch(void* const* d_in, const int* in_sizes, int n_in,
                              void* d_out, int out_size, void* d_ws, size_t ws_size,
                              hipStream_t stream)
{
    const float* nfeats = (const float*)d_in[0];
    const float* efeats = (const float*)d_in[1];
    const int*   src    = (const int*)  d_in[2];
    const int*   dst    = (const int*)  d_in[3];
    const float* W_node = (const float*)d_in[4];
    const float* b_node = (const float*)d_in[5];
    const float* W_ni   = (const float*)d_in[6];
    const float* W_nj   = (const float*)d_in[7];
    const float* W_fij  = (const float*)d_in[8];
    const float* bias   = (const float*)d_in[9];

    float* h_out = (float*)d_out;                   // [NN, F]
    float* f_out = (float*)d_out + (size_t)NN * F;  // [NE, F]

    float* f_ni = (float*)d_ws;
    float* f_nj = f_ni + (size_t)NN * F;
    float* h    = f_nj + (size_t)NN * F;
    float* deg  = h    + (size_t)NN * F;
    if (ws_size < ((size_t)3 * NN * F + NN) * sizeof(float)) return;  // loud failure if ws too small

    hipMemsetAsync(h_out, 0, (size_t)NN * F * sizeof(float), stream);
    hipMemsetAsync(deg,   0, (size_t)NN * sizeof(float), stream);

    node_kernel<<<(NN + 255) / 256, 256, 0, stream>>>(nfeats, W_node, b_node, W_ni, W_nj, f_ni, f_nj, h);
    edge_kernel<<<(NE + 255) / 256, 256, 0, stream>>>(efeats, src, dst, f_ni, f_nj, W_fij, bias, f_out);
    msg_kernel<<<(int)(((long long)NE * 16 + 255) / 256), 256, 0, stream>>>(h, src, dst, h_out, deg);
    final_kernel<<<(NN * F + 255) / 256, 256, 0, stream>>>(h_out, deg);
}

// Round 2
// 1903.568 us; speedup vs baseline: 1.4939x; 1.4939x over previous
//
#include <hip/hip_runtime.h>

#define NN 100000
#define NE 1600000
#define F 64

// ---------------- node transform: f_ni = x@W_ni^T, f_nj = x@W_nj^T, h = x@W_node^T + b ----------------
__global__ __launch_bounds__(256) void node_kernel(
    const float* __restrict__ nfeats,
    const float* __restrict__ W_node, const float* __restrict__ b_node,
    const float* __restrict__ W_ni,   const float* __restrict__ W_nj,
    float* __restrict__ f_ni, float* __restrict__ f_nj, float* __restrict__ h)
{
    const int n = blockIdx.x * 256 + threadIdx.x;
    if (n >= NN) return;
    float x[F];
    const float4* xr = reinterpret_cast<const float4*>(nfeats + (size_t)n * F);
#pragma unroll
    for (int i = 0; i < F / 4; ++i) reinterpret_cast<float4*>(x)[i] = xr[i];

    float4* po = reinterpret_cast<float4*>(f_ni + (size_t)n * F);
    float4* qo = reinterpret_cast<float4*>(f_nj + (size_t)n * F);
    float4* ho = reinterpret_cast<float4*>(h    + (size_t)n * F);

    for (int oc = 0; oc < F; oc += 4) {
        float ai[4], aj[4], ah[4];
#pragma unroll
        for (int j = 0; j < 4; ++j) { ai[j] = 0.f; aj[j] = 0.f; ah[j] = b_node[oc + j]; }
#pragma unroll
        for (int k = 0; k < F; ++k) {
            const float xv = x[k];
#pragma unroll
            for (int j = 0; j < 4; ++j) {
                ai[j] += xv * W_ni  [(oc + j) * F + k];
                aj[j] += xv * W_nj  [(oc + j) * F + k];
                ah[j] += xv * W_node[(oc + j) * F + k];
            }
        }
        po[oc >> 2] = make_float4(ai[0], ai[1], ai[2], ai[3]);
        qo[oc >> 2] = make_float4(aj[0], aj[1], aj[2], aj[3]);
        ho[oc >> 2] = make_float4(ah[0], ah[1], ah[2], ah[3]);
    }
}

// ---------------- edge update: f_out = leaky_relu(f_ni[src] + f_nj[dst] + efeats@W_fij^T + bias) -------
__global__ __launch_bounds__(256) void edge_kernel(
    const float* __restrict__ efeats,
    const int* __restrict__ src, const int* __restrict__ dst,
    const float* __restrict__ f_ni, const float* __restrict__ f_nj,
    const float* __restrict__ W_fij, const float* __restrict__ bias,
    float* __restrict__ f_out)
{
    const int e = blockIdx.x * 256 + threadIdx.x;
    if (e >= NE) return;
    const int s = src[e], d = dst[e];
    float x[F];
    const float4* xr = reinterpret_cast<const float4*>(efeats + (size_t)e * F);
#pragma unroll
    for (int i = 0; i < F / 4; ++i) reinterpret_cast<float4*>(x)[i] = xr[i];

    const float4* gi = reinterpret_cast<const float4*>(f_ni + (size_t)s * F);
    const float4* gj = reinterpret_cast<const float4*>(f_nj + (size_t)d * F);
    float4* out = reinterpret_cast<float4*>(f_out + (size_t)e * F);

    for (int oc = 0; oc < F; oc += 4) {
        float a[4];
#pragma unroll
        for (int j = 0; j < 4; ++j) a[j] = bias[oc + j];
#pragma unroll
        for (int k = 0; k < F; ++k) {
            const float xv = x[k];
#pragma unroll
            for (int j = 0; j < 4; ++j) a[j] += xv * W_fij[(oc + j) * F + k];
        }
        const float4 v1 = gi[oc >> 2];
        const float4 v2 = gj[oc >> 2];
        a[0] += v1.x + v2.x;
        a[1] += v1.y + v2.y;
        a[2] += v1.z + v2.z;
        a[3] += v1.w + v2.w;
#pragma unroll
        for (int j = 0; j < 4; ++j) a[j] = (a[j] > 0.f) ? a[j] : 0.01f * a[j];
        out[oc >> 2] = make_float4(a[0], a[1], a[2], a[3]);
    }
}

// ---------------- CSR build step 1: in-degree histogram ----------------
__global__ __launch_bounds__(256) void hist_kernel(
    const int* __restrict__ dst, int* __restrict__ counts)
{
    const int e = blockIdx.x * 256 + threadIdx.x;
    if (e >= NE) return;
    atomicAdd(&counts[dst[e]], 1);
}

// ---------------- CSR build step 2: exclusive scan (single block, two-pass) ----------------
__global__ __launch_bounds__(1024) void scan_kernel(
    const int* __restrict__ counts, int* __restrict__ offsets, int* __restrict__ cursor)
{
    __shared__ int sdata[1024];
    const int t = threadIdx.x;
    const int CH = (NN + 1023) / 1024;   // 98
    const int base = t * CH;

    int mysum = 0;
    for (int i = 0; i < CH; ++i) {
        const int idx = base + i;
        if (idx < NN) mysum += counts[idx];
    }
    sdata[t] = mysum;
    __syncthreads();
    // Hillis-Steele inclusive scan over 1024 partials
    for (int off = 1; off < 1024; off <<= 1) {
        int v = (t >= off) ? sdata[t - off] : 0;
        __syncthreads();
        sdata[t] += v;
        __syncthreads();
    }
    int running = sdata[t] - mysum;      // exclusive prefix
    for (int i = 0; i < CH; ++i) {
        const int idx = base + i;
        if (idx < NN) {
            offsets[idx] = running;
            cursor[idx]  = running;
            running += counts[idx];
        }
    }
    if (t == 1023) offsets[NN] = running;   // == NE
}

// ---------------- CSR build step 3: placement ----------------
__global__ __launch_bounds__(256) void place_kernel(
    const int* __restrict__ src, const int* __restrict__ dst,
    int* __restrict__ cursor, int* __restrict__ eidx)
{
    const int e = blockIdx.x * 256 + threadIdx.x;
    if (e >= NE) return;
    const int pos = atomicAdd(&cursor[dst[e]], 1);
    eidx[pos] = src[e];
}

// ---------------- aggregation: wave per node, lane = column ----------------
__global__ __launch_bounds__(256) void gather_kernel(
    const float* __restrict__ h, const int* __restrict__ offsets,
    const int* __restrict__ eidx, float* __restrict__ h_out)
{
    const int n = blockIdx.x * 4 + (threadIdx.x >> 6);
    const int lane = threadIdx.x & 63;
    if (n >= NN) return;
    const int beg = offsets[n], end = offsets[n + 1];
    float acc = 0.f;
    int k = beg;
    for (; k + 4 <= end; k += 4) {
        const int s0 = eidx[k], s1 = eidx[k + 1], s2 = eidx[k + 2], s3 = eidx[k + 3];
        const float v0 = h[(size_t)s0 * F + lane];
        const float v1 = h[(size_t)s1 * F + lane];
        const float v2 = h[(size_t)s2 * F + lane];
        const float v3 = h[(size_t)s3 * F + lane];
        acc += v0; acc += v1; acc += v2; acc += v3;
    }
    for (; k < end; ++k) acc += h[(size_t)eidx[k] * F + lane];
    const float deg = (float)(end - beg);
    h_out[(size_t)n * F + lane] = acc / fmaxf(deg, 1.0f);
}

extern "C" void kernel_launch(void* const* d_in, const int* in_sizes, int n_in,
                              void* d_out, int out_size, void* d_ws, size_t ws_size,
                              hipStream_t stream)
{
    const float* nfeats = (const float*)d_in[0];
    const float* efeats = (const float*)d_in[1];
    const int*   src    = (const int*)  d_in[2];
    const int*   dst    = (const int*)  d_in[3];
    const float* W_node = (const float*)d_in[4];
    const float* b_node = (const float*)d_in[5];
    const float* W_ni   = (const float*)d_in[6];
    const float* W_nj   = (const float*)d_in[7];
    const float* W_fij  = (const float*)d_in[8];
    const float* bias   = (const float*)d_in[9];

    float* h_out = (float*)d_out;                   // [NN, F]
    float* f_out = (float*)d_out + (size_t)NN * F;  // [NE, F]

    // workspace layout
    float* f_ni    = (float*)d_ws;
    float* f_nj    = f_ni + (size_t)NN * F;
    float* h       = f_nj + (size_t)NN * F;
    int*   offsets = (int*)(h + (size_t)NN * F);    // NN+1
    int*   cursor  = offsets + (NN + 1);            // NN
    int*   counts  = cursor + NN;                   // NN
    int*   eidx    = counts + NN;                   // NE
    const size_t need = ((size_t)3 * NN * F) * sizeof(float)
                      + ((size_t)(3 * NN + 1) + NE) * sizeof(int);
    if (ws_size < need) return;

    hipMemsetAsync(counts, 0, (size_t)NN * sizeof(int), stream);

    node_kernel<<<(NN + 255) / 256, 256, 0, stream>>>(nfeats, W_node, b_node, W_ni, W_nj, f_ni, f_nj, h);
    edge_kernel<<<(NE + 255) / 256, 256, 0, stream>>>(efeats, src, dst, f_ni, f_nj, W_fij, bias, f_out);
    hist_kernel<<<(NE + 255) / 256, 256, 0, stream>>>(dst, counts);
    scan_kernel<<<1, 1024, 0, stream>>>(counts, offsets, cursor);
    place_kernel<<<(NE + 255) / 256, 256, 0, stream>>>(src, dst, cursor, eidx);
    gather_kernel<<<(NN + 3) / 4, 256, 0, stream>>>(h, offsets, eidx, h_out);
}

// Round 3
// 1811.357 us; speedup vs baseline: 1.5699x; 1.0509x over previous
//
#include <hip/hip_runtime.h>

#define NN 100000
#define NE 1600000
#define F 64

// ---------------- node transform: f_ni = x@W_ni^T, f_nj = x@W_nj^T, h = x@W_node^T + b ----------------
// Block stages 256 node rows into LDS via coalesced float4 loads (rotate-swizzled),
// then lane = node with row in VGPRs; W via wave-uniform scalar loads.
__global__ __launch_bounds__(256) void node_kernel(
    const float* __restrict__ nfeats,
    const float* __restrict__ W_node, const float* __restrict__ b_node,
    const float* __restrict__ W_ni,   const float* __restrict__ W_nj,
    float* __restrict__ f_ni, float* __restrict__ f_nj, float* __restrict__ h)
{
    __shared__ float xs[256 * F];
    const int t = threadIdx.x;
    const int tile0 = blockIdx.x * 256;

    const float4* gsrc = reinterpret_cast<const float4*>(nfeats + (size_t)tile0 * F);
#pragma unroll
    for (int i = 0; i < 16; ++i) {
        const int idx = i * 256 + t;            // float4 index within tile
        const int row = idx >> 4;
        if (tile0 + row < NN) {
            const float4 v = gsrc[idx];
            const int c4 = (idx & 15) << 2;
            const int base = row << 6;
            xs[base + ((c4 + 0 + row) & 63)] = v.x;
            xs[base + ((c4 + 1 + row) & 63)] = v.y;
            xs[base + ((c4 + 2 + row) & 63)] = v.z;
            xs[base + ((c4 + 3 + row) & 63)] = v.w;
        }
    }
    __syncthreads();

    const int n = tile0 + t;
    if (n >= NN) return;

    float x[F];
#pragma unroll
    for (int k = 0; k < F; ++k) x[k] = xs[(t << 6) + ((k + t) & 63)];

    float4* po = reinterpret_cast<float4*>(f_ni + (size_t)n * F);
    float4* qo = reinterpret_cast<float4*>(f_nj + (size_t)n * F);
    float4* ho = reinterpret_cast<float4*>(h    + (size_t)n * F);

    for (int oc = 0; oc < F; oc += 4) {
        float ai[4], aj[4], ah[4];
#pragma unroll
        for (int j = 0; j < 4; ++j) { ai[j] = 0.f; aj[j] = 0.f; ah[j] = b_node[oc + j]; }
#pragma unroll
        for (int k = 0; k < F; ++k) {
            const float xv = x[k];
#pragma unroll
            for (int j = 0; j < 4; ++j) {
                ai[j] += xv * W_ni  [(oc + j) * F + k];
                aj[j] += xv * W_nj  [(oc + j) * F + k];
                ah[j] += xv * W_node[(oc + j) * F + k];
            }
        }
        po[oc >> 2] = make_float4(ai[0], ai[1], ai[2], ai[3]);
        qo[oc >> 2] = make_float4(aj[0], aj[1], aj[2], aj[3]);
        ho[oc >> 2] = make_float4(ah[0], ah[1], ah[2], ah[3]);
    }
}

// ---------------- edge update: f_out = leaky_relu(f_ni[src] + f_nj[dst] + efeats@W_fij^T + bias) -------
// Same LDS-staged coalesced row transport; NE is an exact multiple of 256 (no guards).
__global__ __launch_bounds__(256) void edge_kernel(
    const float* __restrict__ efeats,
    const int* __restrict__ src, const int* __restrict__ dst,
    const float* __restrict__ f_ni, const float* __restrict__ f_nj,
    const float* __restrict__ W_fij, const float* __restrict__ bias,
    float* __restrict__ f_out)
{
    __shared__ float xs[256 * F];
    const int t = threadIdx.x;
    const int tile0 = blockIdx.x * 256;

    const float4* gsrc = reinterpret_cast<const float4*>(efeats + (size_t)tile0 * F);
#pragma unroll
    for (int i = 0; i < 16; ++i) {
        const int idx = i * 256 + t;
        const float4 v = gsrc[idx];
        const int row = idx >> 4;
        const int c4 = (idx & 15) << 2;
        const int base = row << 6;
        xs[base + ((c4 + 0 + row) & 63)] = v.x;
        xs[base + ((c4 + 1 + row) & 63)] = v.y;
        xs[base + ((c4 + 2 + row) & 63)] = v.z;
        xs[base + ((c4 + 3 + row) & 63)] = v.w;
    }
    __syncthreads();

    const int e = tile0 + t;
    const int s = src[e], d = dst[e];

    float x[F];
#pragma unroll
    for (int k = 0; k < F; ++k) x[k] = xs[(t << 6) + ((k + t) & 63)];

    const float4* gi = reinterpret_cast<const float4*>(f_ni + (size_t)s * F);
    const float4* gj = reinterpret_cast<const float4*>(f_nj + (size_t)d * F);
    float4* out = reinterpret_cast<float4*>(f_out + (size_t)e * F);

    for (int oc = 0; oc < F; oc += 4) {
        float a[4];
#pragma unroll
        for (int j = 0; j < 4; ++j) a[j] = bias[oc + j];
#pragma unroll
        for (int k = 0; k < F; ++k) {
            const float xv = x[k];
#pragma unroll
            for (int j = 0; j < 4; ++j) a[j] += xv * W_fij[(oc + j) * F + k];
        }
        const float4 v1 = gi[oc >> 2];
        const float4 v2 = gj[oc >> 2];
        a[0] += v1.x + v2.x;
        a[1] += v1.y + v2.y;
        a[2] += v1.z + v2.z;
        a[3] += v1.w + v2.w;
#pragma unroll
        for (int j = 0; j < 4; ++j) a[j] = (a[j] > 0.f) ? a[j] : 0.01f * a[j];
        out[oc >> 2] = make_float4(a[0], a[1], a[2], a[3]);
    }
}

// ---------------- CSR build step 1: in-degree histogram ----------------
__global__ __launch_bounds__(256) void hist_kernel(
    const int* __restrict__ dst, int* __restrict__ counts)
{
    const int e = blockIdx.x * 256 + threadIdx.x;
    if (e >= NE) return;
    atomicAdd(&counts[dst[e]], 1);
}

// ---------------- CSR build step 2: exclusive scan (single block, two-pass) ----------------
__global__ __launch_bounds__(1024) void scan_kernel(
    const int* __restrict__ counts, int* __restrict__ offsets, int* __restrict__ cursor)
{
    __shared__ int sdata[1024];
    const int t = threadIdx.x;
    const int CH = (NN + 1023) / 1024;   // 98
    const int base = t * CH;

    int mysum = 0;
    for (int i = 0; i < CH; ++i) {
        const int idx = base + i;
        if (idx < NN) mysum += counts[idx];
    }
    sdata[t] = mysum;
    __syncthreads();
    for (int off = 1; off < 1024; off <<= 1) {
        int v = (t >= off) ? sdata[t - off] : 0;
        __syncthreads();
        sdata[t] += v;
        __syncthreads();
    }
    int running = sdata[t] - mysum;      // exclusive prefix
    for (int i = 0; i < CH; ++i) {
        const int idx = base + i;
        if (idx < NN) {
            offsets[idx] = running;
            cursor[idx]  = running;
            running += counts[idx];
        }
    }
    if (t == 1023) offsets[NN] = running;   // == NE
}

// ---------------- CSR build step 3: placement ----------------
__global__ __launch_bounds__(256) void place_kernel(
    const int* __restrict__ src, const int* __restrict__ dst,
    int* __restrict__ cursor, int* __restrict__ eidx)
{
    const int e = blockIdx.x * 256 + threadIdx.x;
    if (e >= NE) return;
    const int pos = atomicAdd(&cursor[dst[e]], 1);
    eidx[pos] = src[e];
}

// ---------------- aggregation: wave per node, lane = column ----------------
__global__ __launch_bounds__(256) void gather_kernel(
    const float* __restrict__ h, const int* __restrict__ offsets,
    const int* __restrict__ eidx, float* __restrict__ h_out)
{
    const int n = blockIdx.x * 4 + (threadIdx.x >> 6);
    const int lane = threadIdx.x & 63;
    if (n >= NN) return;
    const int beg = offsets[n], end = offsets[n + 1];
    float acc = 0.f;
    int k = beg;
    for (; k + 4 <= end; k += 4) {
        const int s0 = eidx[k], s1 = eidx[k + 1], s2 = eidx[k + 2], s3 = eidx[k + 3];
        const float v0 = h[(size_t)s0 * F + lane];
        const float v1 = h[(size_t)s1 * F + lane];
        const float v2 = h[(size_t)s2 * F + lane];
        const float v3 = h[(size_t)s3 * F + lane];
        acc += v0; acc += v1; acc += v2; acc += v3;
    }
    for (; k < end; ++k) acc += h[(size_t)eidx[k] * F + lane];
    const float deg = (float)(end - beg);
    h_out[(size_t)n * F + lane] = acc / fmaxf(deg, 1.0f);
}

extern "C" void kernel_launch(void* const* d_in, const int* in_sizes, int n_in,
                              void* d_out, int out_size, void* d_ws, size_t ws_size,
                              hipStream_t stream)
{
    const float* nfeats = (const float*)d_in[0];
    const float* efeats = (const float*)d_in[1];
    const int*   src    = (const int*)  d_in[2];
    const int*   dst    = (const int*)  d_in[3];
    const float* W_node = (const float*)d_in[4];
    const float* b_node = (const float*)d_in[5];
    const float* W_ni   = (const float*)d_in[6];
    const float* W_nj   = (const float*)d_in[7];
    const float* W_fij  = (const float*)d_in[8];
    const float* bias   = (const float*)d_in[9];

    float* h_out = (float*)d_out;                   // [NN, F]
    float* f_out = (float*)d_out + (size_t)NN * F;  // [NE, F]

    float* f_ni    = (float*)d_ws;
    float* f_nj    = f_ni + (size_t)NN * F;
    float* h       = f_nj + (size_t)NN * F;
    int*   offsets = (int*)(h + (size_t)NN * F);    // NN+1
    int*   cursor  = offsets + (NN + 1);            // NN
    int*   counts  = cursor + NN;                   // NN
    int*   eidx    = counts + NN;                   // NE
    const size_t need = ((size_t)3 * NN * F) * sizeof(float)
                      + ((size_t)(3 * NN + 1) + NE) * sizeof(int);
    if (ws_size < need) return;

    hipMemsetAsync(counts, 0, (size_t)NN * sizeof(int), stream);

    node_kernel<<<(NN + 255) / 256, 256, 0, stream>>>(nfeats, W_node, b_node, W_ni, W_nj, f_ni, f_nj, h);
    edge_kernel<<<NE / 256, 256, 0, stream>>>(efeats, src, dst, f_ni, f_nj, W_fij, bias, f_out);
    hist_kernel<<<(NE + 255) / 256, 256, 0, stream>>>(dst, counts);
    scan_kernel<<<1, 1024, 0, stream>>>(counts, offsets, cursor);
    place_kernel<<<(NE + 255) / 256, 256, 0, stream>>>(src, dst, cursor, eidx);
    gather_kernel<<<(NN + 3) / 4, 256, 0, stream>>>(h, offsets, eidx, h_out);
}

// Round 4
// 1243.728 us; speedup vs baseline: 2.2864x; 1.4564x over previous
//
#include <hip/hip_runtime.h>

#define NN 100000
#define NE 1600000
#define F 64

typedef float f32x4 __attribute__((ext_vector_type(4)));

// ---------------- node transform: f_ni = x@W_ni^T, f_nj = x@W_nj^T, h = x@W_node^T + b ----------------
__global__ __launch_bounds__(256) void node_kernel(
    const float* __restrict__ nfeats,
    const float* __restrict__ W_node, const float* __restrict__ b_node,
    const float* __restrict__ W_ni,   const float* __restrict__ W_nj,
    float* __restrict__ f_ni, float* __restrict__ f_nj, float* __restrict__ h)
{
    __shared__ float xs[256 * F];
    const int t = threadIdx.x;
    const int tile0 = blockIdx.x * 256;

    const f32x4* gsrc = reinterpret_cast<const f32x4*>(nfeats + (size_t)tile0 * F);
#pragma unroll
    for (int i = 0; i < 16; ++i) {
        const int idx = i * 256 + t;
        const int row = idx >> 4;
        if (tile0 + row < NN) {
            const f32x4 v = gsrc[idx];
            const int c4 = (idx & 15) << 2;
            float* b = xs + (row << 6);
            b[(c4 + 0 + row) & 63] = v[0];
            b[(c4 + 1 + row) & 63] = v[1];
            b[(c4 + 2 + row) & 63] = v[2];
            b[(c4 + 3 + row) & 63] = v[3];
        }
    }
    __syncthreads();

    const int n = tile0 + t;
    if (n >= NN) return;

    float x[F];
#pragma unroll
    for (int k = 0; k < F; ++k) x[k] = xs[(t << 6) + ((k + t) & 63)];

    f32x4* po = reinterpret_cast<f32x4*>(f_ni + (size_t)n * F);
    f32x4* qo = reinterpret_cast<f32x4*>(f_nj + (size_t)n * F);
    f32x4* ho = reinterpret_cast<f32x4*>(h    + (size_t)n * F);

    for (int oc = 0; oc < F; oc += 4) {
        float ai[4], aj[4], ah[4];
#pragma unroll
        for (int j = 0; j < 4; ++j) { ai[j] = 0.f; aj[j] = 0.f; ah[j] = b_node[oc + j]; }
#pragma unroll
        for (int k = 0; k < F; ++k) {
            const float xv = x[k];
#pragma unroll
            for (int j = 0; j < 4; ++j) {
                ai[j] += xv * W_ni  [(oc + j) * F + k];
                aj[j] += xv * W_nj  [(oc + j) * F + k];
                ah[j] += xv * W_node[(oc + j) * F + k];
            }
        }
        po[oc >> 2] = f32x4{ai[0], ai[1], ai[2], ai[3]};
        qo[oc >> 2] = f32x4{aj[0], aj[1], aj[2], aj[3]};
        ho[oc >> 2] = f32x4{ah[0], ah[1], ah[2], ah[3]};
    }
}

// ---------------- edge update: f_out = leaky_relu(f_ni[src] + f_nj[dst] + efeats@W_fij^T + bias) -------
// nt streaming in/out, LDS-staged both directions, line-granular gathers.
__global__ __launch_bounds__(256, 2) void edge_kernel(
    const float* __restrict__ efeats,
    const int* __restrict__ src, const int* __restrict__ dst,
    const float* __restrict__ f_ni, const float* __restrict__ f_nj,
    const float* __restrict__ W_fij, const float* __restrict__ bias,
    float* __restrict__ f_out)
{
    __shared__ float xs[256 * F];   // reused: input tile, then output tile
    const int t = threadIdx.x;
    const int tile0 = blockIdx.x * 256;

    // ---- stage-in: linear nontemporal float4 loads, rotate-swizzled LDS writes
    const f32x4* gsrc = reinterpret_cast<const f32x4*>(efeats + (size_t)tile0 * F);
#pragma unroll
    for (int i = 0; i < 16; ++i) {
        const int idx = i * 256 + t;
        const f32x4 v = __builtin_nontemporal_load(gsrc + idx);
        const int row = idx >> 4;
        const int c4 = (idx & 15) << 2;
        float* b = xs + (row << 6);
        b[(c4 + 0 + row) & 63] = v[0];
        b[(c4 + 1 + row) & 63] = v[1];
        b[(c4 + 2 + row) & 63] = v[2];
        b[(c4 + 3 + row) & 63] = v[3];
    }
    const int e = tile0 + t;
    const int s = src[e], d = dst[e];
    __syncthreads();

    float x[F];
#pragma unroll
    for (int k = 0; k < F; ++k) x[k] = xs[(t << 6) + ((k + t) & 63)];
    __syncthreads();            // xs now free for output staging

    const f32x4* gi = reinterpret_cast<const f32x4*>(f_ni + (size_t)s * F);
    const f32x4* gj = reinterpret_cast<const f32x4*>(f_nj + (size_t)d * F);
    float* ob = xs + (t << 6);

#pragma unroll
    for (int half = 0; half < 2; ++half) {
        // one 128B cache line of each gather row, loaded back-to-back, consumed now
        f32x4 vni[8], vnj[8];
#pragma unroll
        for (int i = 0; i < 8; ++i) vni[i] = gi[half * 8 + i];
#pragma unroll
        for (int i = 0; i < 8; ++i) vnj[i] = gj[half * 8 + i];

#pragma unroll
        for (int g = 0; g < 8; ++g) {
            const int oc = half * 32 + g * 4;
            float a[4];
#pragma unroll
            for (int j = 0; j < 4; ++j) a[j] = bias[oc + j];
#pragma unroll
            for (int k = 0; k < F; ++k) {
                const float xv = x[k];
#pragma unroll
                for (int j = 0; j < 4; ++j) a[j] += xv * W_fij[(oc + j) * F + k];
            }
#pragma unroll
            for (int j = 0; j < 4; ++j) {
                float v = a[j] + vni[g][j] + vnj[g][j];
                v = (v > 0.f) ? v : 0.01f * v;
                ob[(oc + j + t) & 63] = v;
            }
        }
    }
    __syncthreads();

    // ---- stage-out: swizzled LDS reads, linear nontemporal float4 stores
    f32x4* gout = reinterpret_cast<f32x4*>(f_out + (size_t)tile0 * F);
#pragma unroll
    for (int i = 0; i < 16; ++i) {
        const int idx = i * 256 + t;
        const int row = idx >> 4;
        const int c4 = (idx & 15) << 2;
        const float* b = xs + (row << 6);
        f32x4 v;
        v[0] = b[(c4 + 0 + row) & 63];
        v[1] = b[(c4 + 1 + row) & 63];
        v[2] = b[(c4 + 2 + row) & 63];
        v[3] = b[(c4 + 3 + row) & 63];
        __builtin_nontemporal_store(v, gout + idx);
    }
}

// ---------------- CSR build step 1: in-degree histogram ----------------
__global__ __launch_bounds__(256) void hist_kernel(
    const int* __restrict__ dst, int* __restrict__ counts)
{
    const int e = blockIdx.x * 256 + threadIdx.x;
    if (e >= NE) return;
    atomicAdd(&counts[dst[e]], 1);
}

// ---------------- CSR build step 2: exclusive scan (single block, two-pass) ----------------
__global__ __launch_bounds__(1024) void scan_kernel(
    const int* __restrict__ counts, int* __restrict__ offsets, int* __restrict__ cursor)
{
    __shared__ int sdata[1024];
    const int t = threadIdx.x;
    const int CH = (NN + 1023) / 1024;   // 98
    const int base = t * CH;

    int mysum = 0;
    for (int i = 0; i < CH; ++i) {
        const int idx = base + i;
        if (idx < NN) mysum += counts[idx];
    }
    sdata[t] = mysum;
    __syncthreads();
    for (int off = 1; off < 1024; off <<= 1) {
        int v = (t >= off) ? sdata[t - off] : 0;
        __syncthreads();
        sdata[t] += v;
        __syncthreads();
    }
    int running = sdata[t] - mysum;      // exclusive prefix
    for (int i = 0; i < CH; ++i) {
        const int idx = base + i;
        if (idx < NN) {
            offsets[idx] = running;
            cursor[idx]  = running;
            running += counts[idx];
        }
    }
    if (t == 1023) offsets[NN] = running;   // == NE
}

// ---------------- CSR build step 3: placement ----------------
__global__ __launch_bounds__(256) void place_kernel(
    const int* __restrict__ src, const int* __restrict__ dst,
    int* __restrict__ cursor, int* __restrict__ eidx)
{
    const int e = blockIdx.x * 256 + threadIdx.x;
    if (e >= NE) return;
    const int pos = atomicAdd(&cursor[dst[e]], 1);
    eidx[pos] = src[e];
}

// ---------------- aggregation: wave per node, lane = column ----------------
__global__ __launch_bounds__(256) void gather_kernel(
    const float* __restrict__ h, const int* __restrict__ offsets,
    const int* __restrict__ eidx, float* __restrict__ h_out)
{
    const int n = blockIdx.x * 4 + (threadIdx.x >> 6);
    const int lane = threadIdx.x & 63;
    if (n >= NN) return;
    const int beg = offsets[n], end = offsets[n + 1];
    float acc = 0.f;
    int k = beg;
    for (; k + 4 <= end; k += 4) {
        const int s0 = eidx[k], s1 = eidx[k + 1], s2 = eidx[k + 2], s3 = eidx[k + 3];
        const float v0 = h[(size_t)s0 * F + lane];
        const float v1 = h[(size_t)s1 * F + lane];
        const float v2 = h[(size_t)s2 * F + lane];
        const float v3 = h[(size_t)s3 * F + lane];
        acc += v0; acc += v1; acc += v2; acc += v3;
    }
    for (; k < end; ++k) acc += h[(size_t)eidx[k] * F + lane];
    const float deg = (float)(end - beg);
    __builtin_nontemporal_store(acc / fmaxf(deg, 1.0f), h_out + (size_t)n * F + lane);
}

extern "C" void kernel_launch(void* const* d_in, const int* in_sizes, int n_in,
                              void* d_out, int out_size, void* d_ws, size_t ws_size,
                              hipStream_t stream)
{
    const float* nfeats = (const float*)d_in[0];
    const float* efeats = (const float*)d_in[1];
    const int*   src    = (const int*)  d_in[2];
    const int*   dst    = (const int*)  d_in[3];
    const float* W_node = (const float*)d_in[4];
    const float* b_node = (const float*)d_in[5];
    const float* W_ni   = (const float*)d_in[6];
    const float* W_nj   = (const float*)d_in[7];
    const float* W_fij  = (const float*)d_in[8];
    const float* bias   = (const float*)d_in[9];

    float* h_out = (float*)d_out;                   // [NN, F]
    float* f_out = (float*)d_out + (size_t)NN * F;  // [NE, F]

    float* f_ni    = (float*)d_ws;
    float* f_nj    = f_ni + (size_t)NN * F;
    float* h       = f_nj + (size_t)NN * F;
    int*   offsets = (int*)(h + (size_t)NN * F);    // NN+1
    int*   cursor  = offsets + (NN + 1);            // NN
    int*   counts  = cursor + NN;                   // NN
    int*   eidx    = counts + NN;                   // NE
    const size_t need = ((size_t)3 * NN * F) * sizeof(float)
                      + ((size_t)(3 * NN + 1) + NE) * sizeof(int);
    if (ws_size < need) return;

    hipMemsetAsync(counts, 0, (size_t)NN * sizeof(int), stream);

    node_kernel<<<(NN + 255) / 256, 256, 0, stream>>>(nfeats, W_node, b_node, W_ni, W_nj, f_ni, f_nj, h);
    edge_kernel<<<NE / 256, 256, 0, stream>>>(efeats, src, dst, f_ni, f_nj, W_fij, bias, f_out);
    hist_kernel<<<(NE + 255) / 256, 256, 0, stream>>>(dst, counts);
    scan_kernel<<<1, 1024, 0, stream>>>(counts, offsets, cursor);
    place_kernel<<<(NE + 255) / 256, 256, 0, stream>>>(src, dst, cursor, eidx);
    gather_kernel<<<(NN + 3) / 4, 256, 0, stream>>>(h, offsets, eidx, h_out);
}